// Round 1
// 257.538 us; speedup vs baseline: 1.0660x; 1.0660x over previous
//
#include <hip/hip_runtime.h>
#include <cstdint>

// Problem sizes (fixed by reference)
#define S_    2048
#define DM    1024
#define DH    4096
#define NTOK  8192     // B*S = 4*2048
#define WELEM 4194304  // 4096*1024 elements in each weight matrix
#define CT    8        // tokens per conv block

typedef int v4i __attribute__((ext_vector_type(4)));
typedef _Float16 half8 __attribute__((ext_vector_type(8)));
typedef char char8v __attribute__((ext_vector_type(8)));

// async global->LDS, 16B per lane, dest = wave-uniform base (+ lane*16 by HW)
#define GLOAD_LDS16(g, l)                                                   \
    __builtin_amdgcn_global_load_lds(                                       \
        (const __attribute__((address_space(1))) void*)(g),                 \
        (__attribute__((address_space(3))) void*)(l), 16, 0, 0)

// raw barrier (no implicit vmcnt(0) drain) + compiler memory fence
static __device__ __forceinline__ void sbar() {
    asm volatile("" ::: "memory");
    __builtin_amdgcn_s_barrier();
    asm volatile("" ::: "memory");
}
#define LGKM0() asm volatile("s_waitcnt lgkmcnt(0)" ::: "memory")
#define VMC6()  asm volatile("s_waitcnt vmcnt(6)" ::: "memory")
#define VMC0()  asm volatile("s_waitcnt vmcnt(0)" ::: "memory")

// ---------------------------------------------------------------------------
// Per-block partial sums of |w| in fp64, both matrices in one launch.
__global__ __launch_bounds__(256) void absmean_partial(const float4* __restrict__ wa,
                                                       const float4* __restrict__ wb,
                                                       double* __restrict__ partial) {
    __shared__ double red[256];
    const float4* w = (blockIdx.x < 1024) ? wa : wb;
    int base = (blockIdx.x & 1023) * 1024;  // in float4 units
    double s = 0.0;
#pragma unroll
    for (int k = 0; k < 4; ++k) {
        float4 v = w[base + (k << 8) + threadIdx.x];
        s += (double)fabsf(v.x) + (double)fabsf(v.y) +
             (double)fabsf(v.z) + (double)fabsf(v.w);
    }
    red[threadIdx.x] = s;
    __syncthreads();
    for (int off = 128; off > 0; off >>= 1) {
        if (threadIdx.x < off) red[threadIdx.x] += red[threadIdx.x + off];
        __syncthreads();
    }
    if (threadIdx.x == 0) partial[blockIdx.x] = red[0];
}

// Deterministic tree-sum of partials; scale = 1/clip(mean,1e-5) fp32.
__global__ __launch_bounds__(256) void finalize_scales(const double* __restrict__ part,
                                                       float* __restrict__ sc) {
    __shared__ double red[1024];
#pragma unroll 1
    for (int m = 0; m < 2; ++m) {
        const double* p = part + m * 1024;
        __syncthreads();
#pragma unroll
        for (int k = 0; k < 4; ++k) red[(k << 8) + threadIdx.x] = p[(k << 8) + threadIdx.x];
        __syncthreads();
        double s = red[threadIdx.x] + red[threadIdx.x + 256] +
                   red[threadIdx.x + 512] + red[threadIdx.x + 768];
        __syncthreads();
        red[threadIdx.x] = s;
        __syncthreads();
        for (int off = 128; off > 0; off >>= 1) {
            if (threadIdx.x < off) red[threadIdx.x] += red[threadIdx.x + off];
            __syncthreads();
        }
        if (threadIdx.x == 0) {
            double mean = red[0] / (double)WELEM;
            float mf = fmaxf((float)mean, 1e-5f);
            float scale = 1.0f / mf;
            sc[2 * m]     = scale;
            sc[2 * m + 1] = 1.0f / scale;
        }
    }
}

// One launch: blocks [0,8192) ternary-quantize w1/w2; [8192,16384) int8-quantize x.
__global__ __launch_bounds__(256) void quant_all(const float4* __restrict__ w1,
                                                 const float4* __restrict__ w2,
                                                 const float4* __restrict__ x,
                                                 char4* __restrict__ qw1,
                                                 char4* __restrict__ qw2,
                                                 char4* __restrict__ qx,
                                                 float* __restrict__ dqx,
                                                 const float* __restrict__ sc) {
    __shared__ float red[256];
    if (blockIdx.x < 8192) {
        bool second = blockIdx.x >= 4096;
        const float4* w = second ? w2 : w1;
        char4* q = second ? qw2 : qw1;
        float scale = sc[second ? 2 : 0];
        int i = (blockIdx.x & 4095) * 256 + threadIdx.x;
        float4 v = w[i];
        char4 o;
        o.x = (signed char)(int)fminf(fmaxf(rintf(v.x * scale), -1.f), 1.f);
        o.y = (signed char)(int)fminf(fmaxf(rintf(v.y * scale), -1.f), 1.f);
        o.z = (signed char)(int)fminf(fmaxf(rintf(v.z * scale), -1.f), 1.f);
        o.w = (signed char)(int)fminf(fmaxf(rintf(v.w * scale), -1.f), 1.f);
        q[i] = o;
    } else {
        int t = blockIdx.x - 8192;
        float4 v = x[(size_t)t * 256 + threadIdx.x];
        float mx = fmaxf(fmaxf(fabsf(v.x), fabsf(v.y)), fmaxf(fabsf(v.z), fabsf(v.w)));
        red[threadIdx.x] = mx;
        __syncthreads();
        for (int off = 128; off > 0; off >>= 1) {
            if (threadIdx.x < off) red[threadIdx.x] = fmaxf(red[threadIdx.x], red[threadIdx.x + off]);
            __syncthreads();
        }
        float scale = 127.0f / fmaxf(red[0], 1e-5f);
        char4 o;
        o.x = (signed char)(int)fminf(fmaxf(rintf(v.x * scale), -128.f), 127.f);
        o.y = (signed char)(int)fminf(fmaxf(rintf(v.y * scale), -128.f), 127.f);
        o.z = (signed char)(int)fminf(fmaxf(rintf(v.z * scale), -128.f), 127.f);
        o.w = (signed char)(int)fminf(fmaxf(rintf(v.w * scale), -128.f), 127.f);
        qx[(size_t)t * 256 + threadIdx.x] = o;
        if (threadIdx.x == 0) dqx[t] = 1.0f / scale;
    }
}

// Fused depthwise conv3 (+bias) + SiLU + per-token int8 quant over DH=4096.
__global__ __launch_bounds__(512) void conv_silu_quant(const half8* __restrict__ h,
                                                       const float4* __restrict__ cwv,
                                                       const float4* __restrict__ cbv,
                                                       char8v* __restrict__ q,
                                                       float* __restrict__ dq) {
    __shared__ float red[2][8];
    const int tid = threadIdx.x;
    const int t0 = blockIdx.x * CT;
    const int s0 = t0 & (S_ - 1);      // CT | S_, block never straddles batches

    float wc[24], bs[8];
    {
        float4 tmp;
#pragma unroll
        for (int i = 0; i < 6; ++i) {
            tmp = cwv[tid * 6 + i];
            wc[4 * i] = tmp.x; wc[4 * i + 1] = tmp.y; wc[4 * i + 2] = tmp.z; wc[4 * i + 3] = tmp.w;
        }
        tmp = cbv[tid * 2];     bs[0] = tmp.x; bs[1] = tmp.y; bs[2] = tmp.z; bs[3] = tmp.w;
        tmp = cbv[tid * 2 + 1]; bs[4] = tmp.x; bs[5] = tmp.y; bs[6] = tmp.z; bs[7] = tmp.w;
    }

    auto ldrow = [&](int t, bool valid, float* dst) {
        if (valid) {
            half8 raw = h[(size_t)t * 512 + tid];
#pragma unroll
            for (int e = 0; e < 8; ++e) dst[e] = (float)raw[e];
        } else {
#pragma unroll
            for (int e = 0; e < 8; ++e) dst[e] = 0.f;
        }
    };

    float pv[8], cu[8], nx[8], pf[8];
    ldrow(t0 - 1, s0 > 0, pv);
    ldrow(t0, true, cu);
    ldrow(t0 + 1, true, nx);

#pragma unroll
    for (int i = 0; i < CT; ++i) {
        const int t = t0 + i;
        ldrow(t + 2, (s0 + i + 2) < S_, pf);

        float v[8];
        float mx = 0.f;
#pragma unroll
        for (int e = 0; e < 8; ++e) {
            float y = wc[3 * e] * pv[e] + wc[3 * e + 1] * cu[e] + wc[3 * e + 2] * nx[e] + bs[e];
            float r = y / (1.0f + expf(-y));
            v[e] = r;
            mx = fmaxf(mx, fabsf(r));
        }
#pragma unroll
        for (int off = 32; off > 0; off >>= 1)
            mx = fmaxf(mx, __shfl_down(mx, off, 64));
        if ((tid & 63) == 0) red[i & 1][tid >> 6] = mx;
        __syncthreads();
        float rmax = red[i & 1][0];
#pragma unroll
        for (int w = 1; w < 8; ++w) rmax = fmaxf(rmax, red[i & 1][w]);
        float scale = 127.0f / fmaxf(rmax, 1e-5f);
        char8v o;
#pragma unroll
        for (int e = 0; e < 8; ++e)
            o[e] = (signed char)(int)fminf(fmaxf(rintf(v[e] * scale), -128.f), 127.f);
        q[(size_t)t * 512 + tid] = o;
        if (tid == 0) dq[t] = 1.0f / scale;
#pragma unroll
        for (int e = 0; e < 8; ++e) { pv[e] = cu[e]; cu[e] = nx[e]; nx[e] = pf[e]; }
    }
}

// ---------------------------------------------------------------------------
// int8 x ternary GEMM, barrier-lockstep 3-deep pipelined (8-phase-template port):
//   C[m,n] = (sum_k A[m,k]*B[n,k]) * rowdq[m] * sc[slot]
// BM=256, BN=128, BK=128. 8 waves as 4M x 2N, wave tile 64x64,
// acc 4x4 of mfma_i32_16x16x64_i8. 3-buffer LDS ring (3 x 48KB = 144KB),
// global_load_lds width-16 staging (6 DMA/wave/K-tile), counted vmcnt(6)
// placed BEFORE the trailing barrier of each K-tile: the barrier turns the
// per-wave vmcnt guarantee into a cross-wave one (every wave passed its own
// vmcnt before anyone ds_reads the tile). Loads stay 2 K-tiles in flight --
// never drained to 0 in the main loop (T4).
// T2 swizzle: LDS rows are 128B; frag reads (16 rows x same 16B col) would be
// 16-way bank-conflicted. Linear DMA dest + inverse-swizzled GLOBAL source
// (chunk ^= row&7) + same XOR on the ds_read address (both-sides rule).
// Buffer recycle is race-free by construction: tile t+2 (buf (t-1)%3) is
// first staged at (t,ph0), after the trailing barrier of (t-1,ph1) whose
// lgkmcnt(0) precedes it in every wave.
template <typename OutT>
__global__ __launch_bounds__(512, 2) void gemm_i8_3s(const int8_t* __restrict__ A,
                                                     const int8_t* __restrict__ Bm,
                                                     OutT* __restrict__ C,
                                                     const float* __restrict__ rowdq,
                                                     const float* __restrict__ sc, int slot,
                                                     int N, int K) {
    __shared__ __align__(16) int8_t lds[3][49152];   // [buf][A 32KB | B 16KB]
    const int tid  = threadIdx.x;
    const int lane = tid & 63;
    const int wave = tid >> 6;
    const int mbase = blockIdx.y << 8;   // BM=256
    const int nbase = blockIdx.x << 7;   // BN=128
    const int NT = K >> 7;               // K-tiles of 128

    const int wm = wave >> 1;            // 0..3  (m quadrant, 64 rows)
    const int wn = wave & 1;             // 0..1  (n half, 64 cols)

    // ---- staging addressing: thread t covers (row = L*64 + (t>>3), 16B chunk)
    // LDS linear dest = t*16  ->  phys (row = t>>3, pchunk = t&7);
    // content must be logical chunk = pchunk ^ (row&7)  (involution).
    const int srow  = tid >> 3;                       // 0..63 within a load
    const int lchnk = (tid & 7) ^ (srow & 7);
    const int8_t* Ag = A  + (size_t)(mbase + srow) * K + (lchnk << 4);
    const int8_t* Bg = Bm + (size_t)(nbase + srow) * K + (lchnk << 4);
    const size_t rstep = (size_t)64 * K;              // 64 rows

    auto stage = [&](int s, int t, int half) {
        const size_t ko = (size_t)t << 7;
        int8_t* db = &lds[s][wave << 10];             // wave-uniform base
        if (half == 0) {
            GLOAD_LDS16(Ag + ko,               db);
            GLOAD_LDS16(Ag + ko + rstep,       db + 8192);
            GLOAD_LDS16(Ag + ko + 2 * rstep,   db + 16384);
        } else {
            GLOAD_LDS16(Ag + ko + 3 * rstep,   db + 24576);
            GLOAD_LDS16(Bg + ko,               db + 32768);
            GLOAD_LDS16(Bg + ko + rstep,       db + 40960);
        }
    };

    // ---- frag-read addressing (matches i8 16x16x64 layout: row=lane&15,
    // 16B chunk = ksub*4 + (lane>>4)); phys chunk = chunk ^ (row&7) = ^ (lane&7)
    const int fc0 = (((lane >> 4)    ) ^ (lane & 7)) << 4;   // k-sub 0
    const int fc1 = (((lane >> 4) | 4) ^ (lane & 7)) << 4;   // k-sub 1
    const int aro = ((wm << 6) + (lane & 15)) << 7;          // A row byte off
    const int bro = 32768 + (((wn << 6) + (lane & 15)) << 7);// B row byte off

    v4i acc[4][4] = {};

    // prologue: 2 K-tiles in flight, then wait tile0 + barrier (cross-wave)
    stage(0, 0, 0); stage(0, 0, 1);
    if (NT > 1) { stage(1, 1, 0); stage(1, 1, 1); }
    if (NT > 1) VMC6(); else VMC0();
    sbar();

    int sb = 0;
    for (int t = 0; t < NT; ++t) {
        const int8_t* base = &lds[sb][0];
        int s2 = sb + 2; if (s2 >= 3) s2 -= 3;

        // ---------------- phase 0 (k-sub 0) ----------------
        v4i af[4], bf[4];
#pragma unroll
        for (int i = 0; i < 4; ++i)
            af[i] = *reinterpret_cast<const v4i*>(base + aro + (i << 11) + fc0);
#pragma unroll
        for (int j = 0; j < 4; ++j)
            bf[j] = *reinterpret_cast<const v4i*>(base + bro + (j << 11) + fc0);
        if (t + 2 < NT) stage(s2, t + 2, 0);
        sbar();
        LGKM0();
        __builtin_amdgcn_s_setprio(1);
#pragma unroll
        for (int i = 0; i < 4; ++i)
#pragma unroll
            for (int j = 0; j < 4; ++j)
                acc[i][j] = __builtin_amdgcn_mfma_i32_16x16x64_i8(af[i], bf[j], acc[i][j], 0, 0, 0);
        __builtin_amdgcn_s_setprio(0);
        sbar();

        // ---------------- phase 1 (k-sub 1) ----------------
#pragma unroll
        for (int i = 0; i < 4; ++i)
            af[i] = *reinterpret_cast<const v4i*>(base + aro + (i << 11) + fc1);
#pragma unroll
        for (int j = 0; j < 4; ++j)
            bf[j] = *reinterpret_cast<const v4i*>(base + bro + (j << 11) + fc1);
        if (t + 2 < NT) stage(s2, t + 2, 1);
        sbar();
        LGKM0();
        __builtin_amdgcn_s_setprio(1);
#pragma unroll
        for (int i = 0; i < 4; ++i)
#pragma unroll
            for (int j = 0; j < 4; ++j)
                acc[i][j] = __builtin_amdgcn_mfma_i32_16x16x64_i8(af[i], bf[j], acc[i][j], 0, 0, 0);
        __builtin_amdgcn_s_setprio(0);
        // counted wait for NEXT tile's loads, BEFORE the barrier that gates
        // next tile's ds_reads (barrier makes it cross-wave safe)
        if (t + 2 < NT)      VMC6();
        else if (t + 1 < NT) VMC0();
        sbar();

        if (++sb == 3) sb = 0;
    }

    // ---------------- epilogue ----------------
    const float wdq = sc[slot];
    const int quad = lane >> 4;
    const int col  = lane & 15;
#pragma unroll
    for (int i = 0; i < 4; ++i) {
#pragma unroll
        for (int r = 0; r < 4; ++r) {
            int m = mbase + (wm << 6) + (i << 4) + (quad << 2) + r;  // row=(lane>>4)*4+reg
            float rs = rowdq[m] * wdq;
#pragma unroll
            for (int j = 0; j < 4; ++j) {
                int n = nbase + (wn << 6) + (j << 4) + col;          // col=lane&15
                C[(size_t)m * N + n] = (OutT)((float)acc[i][j][r] * rs);
            }
        }
    }
}

// ---------------------------------------------------------------------------
extern "C" void kernel_launch(void* const* d_in, const int* in_sizes, int n_in,
                              void* d_out, int out_size, void* d_ws, size_t ws_size,
                              hipStream_t stream) {
    const float* x  = (const float*)d_in[0];  // [4,2048,1024]
    const float* w1 = (const float*)d_in[1];  // [4096,1024]
    const float* cw = (const float*)d_in[2];  // [4096,1,3]
    const float* cb = (const float*)d_in[3];  // [4096]
    const float* w2 = (const float*)d_in[4];  // [1024,4096]
    float* out = (float*)d_out;               // [4,2048,1024]
    char* ws = (char*)d_ws;

    // Workspace layout (16B-aligned)
    double* part  = (double*)(ws + 0);          // 2048 doubles
    float*  sc    = (float*)(ws + 16384);       // {scale_w1, dq_w1, scale_w2, dq_w2}
    float*  dqx   = (float*)(ws + 16640);       // 8192 floats
    float*  dqh   = (float*)(ws + 49408);       // 8192 floats
    int8_t* qw1   = (int8_t*)(ws + 82176);      // 4 MB
    int8_t* qw2   = (int8_t*)(ws + 4276480);    // 4 MB
    int8_t* qx    = (int8_t*)(ws + 8470784);    // 8 MB
    int8_t* qh    = (int8_t*)(ws + 16859392);   // 32 MB
    _Float16* h   = (_Float16*)(ws + 50413824); // 64 MB (fp16)

    absmean_partial<<<2048, 256, 0, stream>>>((const float4*)w1, (const float4*)w2, part);
    finalize_scales<<<1, 256, 0, stream>>>(part, sc);
    quant_all<<<16384, 256, 0, stream>>>((const float4*)w1, (const float4*)w2,
                                         (const float4*)x, (char4*)qw1, (char4*)qw2,
                                         (char4*)qx, dqx, sc);

    // GEMM1: M=8192, N=4096, K=1024 -> h (fp16)
    dim3 g1(DH / 128, NTOK / 256);
    gemm_i8_3s<_Float16><<<g1, 512, 0, stream>>>(qx, qw1, h, dqx, sc, 1, DH, DM);

    conv_silu_quant<<<NTOK / CT, 512, 0, stream>>>((const half8*)h, (const float4*)cw,
                                                   (const float4*)cb, (char8v*)qh, dqh);

    // GEMM2: M=8192, N=1024, K=4096 -> out (fp32)
    dim3 g2(DM / 128, NTOK / 256);
    gemm_i8_3s<float><<<g2, 512, 0, stream>>>(qh, qw2, out, dqh, sc, 3, DM, DH);
}

// Round 2
// 247.108 us; speedup vs baseline: 1.1110x; 1.0422x over previous
//
#include <hip/hip_runtime.h>
#include <cstdint>

// Problem sizes (fixed by reference)
#define S_    2048
#define DM    1024
#define DH    4096
#define NTOK  8192     // B*S = 4*2048
#define WELEM 4194304  // 4096*1024 elements in each weight matrix
#define CT    8        // tokens per conv block

typedef int v4i __attribute__((ext_vector_type(4)));
typedef _Float16 half8 __attribute__((ext_vector_type(8)));
typedef char char8v __attribute__((ext_vector_type(8)));

// async global->LDS, 16B per lane, dest = wave-uniform base (+ lane*16 by HW)
#define GLOAD_LDS16(g, l)                                                   \
    __builtin_amdgcn_global_load_lds(                                       \
        (const __attribute__((address_space(1))) void*)(g),                 \
        (__attribute__((address_space(3))) void*)(l), 16, 0, 0)

// raw barrier (no implicit vmcnt(0) drain) + compiler memory fence
static __device__ __forceinline__ void sbar() {
    asm volatile("" ::: "memory");
    __builtin_amdgcn_s_barrier();
    asm volatile("" ::: "memory");
}
#define VMC0() asm volatile("s_waitcnt vmcnt(0)" ::: "memory")
#define VMC3() asm volatile("s_waitcnt vmcnt(3)" ::: "memory")
#define VMC4() asm volatile("s_waitcnt vmcnt(4)" ::: "memory")

// ---------------------------------------------------------------------------
// Per-block partial sums of |w| in fp64, both matrices in one launch.
__global__ __launch_bounds__(256) void absmean_partial(const float4* __restrict__ wa,
                                                       const float4* __restrict__ wb,
                                                       double* __restrict__ partial) {
    __shared__ double red[256];
    const float4* w = (blockIdx.x < 1024) ? wa : wb;
    int base = (blockIdx.x & 1023) * 1024;  // in float4 units
    double s = 0.0;
#pragma unroll
    for (int k = 0; k < 4; ++k) {
        float4 v = w[base + (k << 8) + threadIdx.x];
        s += (double)fabsf(v.x) + (double)fabsf(v.y) +
             (double)fabsf(v.z) + (double)fabsf(v.w);
    }
    red[threadIdx.x] = s;
    __syncthreads();
    for (int off = 128; off > 0; off >>= 1) {
        if (threadIdx.x < off) red[threadIdx.x] += red[threadIdx.x + off];
        __syncthreads();
    }
    if (threadIdx.x == 0) partial[blockIdx.x] = red[0];
}

// Deterministic tree-sum of partials; scale = 1/clip(mean,1e-5) fp32.
__global__ __launch_bounds__(256) void finalize_scales(const double* __restrict__ part,
                                                       float* __restrict__ sc) {
    __shared__ double red[1024];
#pragma unroll 1
    for (int m = 0; m < 2; ++m) {
        const double* p = part + m * 1024;
        __syncthreads();
#pragma unroll
        for (int k = 0; k < 4; ++k) red[(k << 8) + threadIdx.x] = p[(k << 8) + threadIdx.x];
        __syncthreads();
        double s = red[threadIdx.x] + red[threadIdx.x + 256] +
                   red[threadIdx.x + 512] + red[threadIdx.x + 768];
        __syncthreads();
        red[threadIdx.x] = s;
        __syncthreads();
        for (int off = 128; off > 0; off >>= 1) {
            if (threadIdx.x < off) red[threadIdx.x] += red[threadIdx.x + off];
            __syncthreads();
        }
        if (threadIdx.x == 0) {
            double mean = red[0] / (double)WELEM;
            float mf = fmaxf((float)mean, 1e-5f);
            float scale = 1.0f / mf;
            sc[2 * m]     = scale;
            sc[2 * m + 1] = 1.0f / scale;
        }
    }
}

// One launch: blocks [0,8192) ternary-quantize w1/w2; [8192,16384) int8-quantize x.
__global__ __launch_bounds__(256) void quant_all(const float4* __restrict__ w1,
                                                 const float4* __restrict__ w2,
                                                 const float4* __restrict__ x,
                                                 char4* __restrict__ qw1,
                                                 char4* __restrict__ qw2,
                                                 char4* __restrict__ qx,
                                                 float* __restrict__ dqx,
                                                 const float* __restrict__ sc) {
    __shared__ float red[256];
    if (blockIdx.x < 8192) {
        bool second = blockIdx.x >= 4096;
        const float4* w = second ? w2 : w1;
        char4* q = second ? qw2 : qw1;
        float scale = sc[second ? 2 : 0];
        int i = (blockIdx.x & 4095) * 256 + threadIdx.x;
        float4 v = w[i];
        char4 o;
        o.x = (signed char)(int)fminf(fmaxf(rintf(v.x * scale), -1.f), 1.f);
        o.y = (signed char)(int)fminf(fmaxf(rintf(v.y * scale), -1.f), 1.f);
        o.z = (signed char)(int)fminf(fmaxf(rintf(v.z * scale), -1.f), 1.f);
        o.w = (signed char)(int)fminf(fmaxf(rintf(v.w * scale), -1.f), 1.f);
        q[i] = o;
    } else {
        int t = blockIdx.x - 8192;
        float4 v = x[(size_t)t * 256 + threadIdx.x];
        float mx = fmaxf(fmaxf(fabsf(v.x), fabsf(v.y)), fmaxf(fabsf(v.z), fabsf(v.w)));
        red[threadIdx.x] = mx;
        __syncthreads();
        for (int off = 128; off > 0; off >>= 1) {
            if (threadIdx.x < off) red[threadIdx.x] = fmaxf(red[threadIdx.x], red[threadIdx.x + off]);
            __syncthreads();
        }
        float scale = 127.0f / fmaxf(red[0], 1e-5f);
        char4 o;
        o.x = (signed char)(int)fminf(fmaxf(rintf(v.x * scale), -128.f), 127.f);
        o.y = (signed char)(int)fminf(fmaxf(rintf(v.y * scale), -128.f), 127.f);
        o.z = (signed char)(int)fminf(fmaxf(rintf(v.z * scale), -128.f), 127.f);
        o.w = (signed char)(int)fminf(fmaxf(rintf(v.w * scale), -128.f), 127.f);
        qx[(size_t)t * 256 + threadIdx.x] = o;
        if (threadIdx.x == 0) dqx[t] = 1.0f / scale;
    }
}

// Fused depthwise conv3 (+bias) + SiLU + per-token int8 quant over DH=4096.
__global__ __launch_bounds__(512) void conv_silu_quant(const half8* __restrict__ h,
                                                       const float4* __restrict__ cwv,
                                                       const float4* __restrict__ cbv,
                                                       char8v* __restrict__ q,
                                                       float* __restrict__ dq) {
    __shared__ float red[2][8];
    const int tid = threadIdx.x;
    const int t0 = blockIdx.x * CT;
    const int s0 = t0 & (S_ - 1);      // CT | S_, block never straddles batches

    float wc[24], bs[8];
    {
        float4 tmp;
#pragma unroll
        for (int i = 0; i < 6; ++i) {
            tmp = cwv[tid * 6 + i];
            wc[4 * i] = tmp.x; wc[4 * i + 1] = tmp.y; wc[4 * i + 2] = tmp.z; wc[4 * i + 3] = tmp.w;
        }
        tmp = cbv[tid * 2];     bs[0] = tmp.x; bs[1] = tmp.y; bs[2] = tmp.z; bs[3] = tmp.w;
        tmp = cbv[tid * 2 + 1]; bs[4] = tmp.x; bs[5] = tmp.y; bs[6] = tmp.z; bs[7] = tmp.w;
    }

    auto ldrow = [&](int t, bool valid, float* dst) {
        if (valid) {
            half8 raw = h[(size_t)t * 512 + tid];
#pragma unroll
            for (int e = 0; e < 8; ++e) dst[e] = (float)raw[e];
        } else {
#pragma unroll
            for (int e = 0; e < 8; ++e) dst[e] = 0.f;
        }
    };

    float pv[8], cu[8], nx[8], pf[8];
    ldrow(t0 - 1, s0 > 0, pv);
    ldrow(t0, true, cu);
    ldrow(t0 + 1, true, nx);

#pragma unroll
    for (int i = 0; i < CT; ++i) {
        const int t = t0 + i;
        ldrow(t + 2, (s0 + i + 2) < S_, pf);

        float v[8];
        float mx = 0.f;
#pragma unroll
        for (int e = 0; e < 8; ++e) {
            float y = wc[3 * e] * pv[e] + wc[3 * e + 1] * cu[e] + wc[3 * e + 2] * nx[e] + bs[e];
            float r = y / (1.0f + expf(-y));
            v[e] = r;
            mx = fmaxf(mx, fabsf(r));
        }
#pragma unroll
        for (int off = 32; off > 0; off >>= 1)
            mx = fmaxf(mx, __shfl_down(mx, off, 64));
        if ((tid & 63) == 0) red[i & 1][tid >> 6] = mx;
        __syncthreads();
        float rmax = red[i & 1][0];
#pragma unroll
        for (int w = 1; w < 8; ++w) rmax = fmaxf(rmax, red[i & 1][w]);
        float scale = 127.0f / fmaxf(rmax, 1e-5f);
        char8v o;
#pragma unroll
        for (int e = 0; e < 8; ++e)
            o[e] = (signed char)(int)fminf(fmaxf(rintf(v[e] * scale), -128.f), 127.f);
        q[(size_t)t * 512 + tid] = o;
        if (tid == 0) dq[t] = 1.0f / scale;
#pragma unroll
        for (int e = 0; e < 8; ++e) { pv[e] = cu[e]; cu[e] = nx[e]; nx[e] = pf[e]; }
    }
}

// ---------------------------------------------------------------------------
// int8 x ternary GEMM, BK=64, one barrier per K-tile, 3-deep ring, occupancy-
// first:  C[m,n] = (sum_k A[m,k]*B[n,k]) * rowdq[m] * sc[slot]
//
// BM=256/W=8 (GEMM1): ring 3 x 24KB = 72KB -> 2 blocks/CU (4 waves/SIMD).
// BM=128/W=4 (GEMM2): ring 3 x 16KB = 48KB -> 3 blocks/CU; grid 512 (full CU
// coverage at N=1024, which BN-only tiling couldn't give).
// Cross-BLOCK overlap is the lever this round: round-1 profile showed 57%
// idle at 1 block/CU (MfmaUtil 23 + VALUBusy 20) -- lockstep barriers with
// nothing else resident expose every stall.
//
// Protocol (single barrier per tile, counted vmcnt never 0 mid-loop):
//   tile t: ds_read frags(buf t%3) | stage(t+2 -> buf (t+2)%3) |
//           16 x mfma (compiler-inserted fine lgkmcnt) | vmcnt(L) | s_barrier
// Recycle safety: any wave past barrier(t) finished its MFMAs(t), hence its
// ds_reads(t) completed; stage(t+3) into buf t%3 is issued only after
// barrier(t). vmcnt(L) at barrier(t) retires tile t+1's loads (its own L
// newest, tile t+2's, remain in flight); barrier makes that cross-wave safe.
//
// Swizzle (64B LDS rows): phys_chunk = chunk ^ ((row>>1)&3). Involution,
// applied on the global staging source (linear DMA dest) and on ds_read.
// 16-lane frag groups spread over all 8 bank-slot classes exactly 2x
// (2-way aliasing is free, m136).
template <int BM, int WAVES, typename OutT>
__global__ __launch_bounds__(WAVES * 64, (BM == 256) ? 4 : 3)
void gemm_i8_bk64(const int8_t* __restrict__ A, const int8_t* __restrict__ Bm,
                  OutT* __restrict__ C, const float* __restrict__ rowdq,
                  const float* __restrict__ sc, int slot, int N, int K) {
    constexpr int BN = 128;
    constexpr int ABYTES = BM * 64;           // A bytes per ring buffer
    constexpr int BUF = (BM + BN) * 64;       // bytes per ring buffer
    constexpr int ALOADS = BM / 16 / WAVES;   // per-wave 1KB A loads per tile
    constexpr int BLOADS = BN / 16 / WAVES;   // per-wave 1KB B loads per tile
    constexpr int L = ALOADS + BLOADS;        // per-wave loads per tile

    __shared__ __align__(16) int8_t lds[3][BUF];
    const int tid  = threadIdx.x;
    const int lane = tid & 63;
    const int wave = tid >> 6;

    // XCD-chunked bijective swizzle (both grids are multiples of 8)
    const int nwg = gridDim.x * gridDim.y;
    int flat = blockIdx.y * gridDim.x + blockIdx.x;
    flat = (flat & 7) * (nwg >> 3) + (flat >> 3);
    const int bx = flat % gridDim.x;
    const int by = flat / gridDim.x;
    const int mbase = by * BM;
    const int nbase = bx << 7;
    const int NT = K >> 6;

    const int wm = wave >> 1;                 // m 64-row slab
    const int wn = wave & 1;                  // n 64-col half

    // ---- staging source addressing (inverse swizzle on global side)
    const int srow = lane >> 2;                               // row within 1KB load
    const int csrc = (((lane & 3) ^ ((lane >> 3) & 3)) << 4); // logical 16B chunk
    const int8_t* Ag = A  + (size_t)(mbase + wave * (ALOADS * 16) + srow) * K + csrc;
    const int8_t* Bg = Bm + (size_t)(nbase + wave * (BLOADS * 16) + srow) * K + csrc;

    auto stage = [&](int s, int tt) {
        const size_t ko = (size_t)tt << 6;
        int8_t* dA = &lds[s][(wave * ALOADS) << 10];
        int8_t* dB = &lds[s][ABYTES + ((wave * BLOADS) << 10)];
#pragma unroll
        for (int l = 0; l < ALOADS; ++l)
            GLOAD_LDS16(Ag + ko + (size_t)(l * 16) * K, dA + (l << 10));
#pragma unroll
        for (int l = 0; l < BLOADS; ++l)
            GLOAD_LDS16(Bg + ko + (size_t)(l * 16) * K, dB + (l << 10));
    };

    // ---- frag read offsets (i8 16x16x64: row = lane&15, chunk = lane>>4)
    const int fc   = (((lane >> 4) ^ ((lane >> 1) & 3)) << 4);  // swizzled chunk
    const int aoff = ((wm * 64 + (lane & 15)) << 6) + fc;       // + i*1024
    const int boff = ABYTES + ((wn * 64 + (lane & 15)) << 6) + fc;

    v4i acc[4][4] = {};

    // prologue: 2 tiles in flight; wait tile 0 (counted), cross-wave via barrier
    stage(0, 0);
    stage(1, 1);
    if constexpr (L == 3) VMC3(); else VMC4();
    sbar();

    int sb = 0;
    for (int t = 0; t < NT; ++t) {
        const int8_t* base = &lds[sb][0];
        v4i af[4], bf[4];
#pragma unroll
        for (int i = 0; i < 4; ++i)
            af[i] = *reinterpret_cast<const v4i*>(base + aoff + (i << 10));
#pragma unroll
        for (int j = 0; j < 4; ++j)
            bf[j] = *reinterpret_cast<const v4i*>(base + boff + (j << 10));
        int s2 = sb + 2; if (s2 >= 3) s2 -= 3;
        if (t + 2 < NT) stage(s2, t + 2);

        __builtin_amdgcn_s_setprio(1);
#pragma unroll
        for (int i = 0; i < 4; ++i)
#pragma unroll
            for (int j = 0; j < 4; ++j)
                acc[i][j] = __builtin_amdgcn_mfma_i32_16x16x64_i8(af[i], bf[j], acc[i][j], 0, 0, 0);
        __builtin_amdgcn_s_setprio(0);

        if (t + 2 < NT)      { if constexpr (L == 3) VMC3(); else VMC4(); }
        else if (t + 1 < NT) VMC0();
        sbar();
        if (++sb == 3) sb = 0;
    }

    // ---------------- epilogue ----------------
    const float wdq = sc[slot];
    const int quad = lane >> 4;
    const int col  = lane & 15;
#pragma unroll
    for (int i = 0; i < 4; ++i) {
#pragma unroll
        for (int r = 0; r < 4; ++r) {
            int m = mbase + (wm << 6) + (i << 4) + (quad << 2) + r;  // row=(lane>>4)*4+reg
            float rs = rowdq[m] * wdq;
#pragma unroll
            for (int j = 0; j < 4; ++j) {
                int n = nbase + (wn << 6) + (j << 4) + col;          // col=lane&15
                C[(size_t)m * N + n] = (OutT)((float)acc[i][j][r] * rs);
            }
        }
    }
}

// ---------------------------------------------------------------------------
extern "C" void kernel_launch(void* const* d_in, const int* in_sizes, int n_in,
                              void* d_out, int out_size, void* d_ws, size_t ws_size,
                              hipStream_t stream) {
    const float* x  = (const float*)d_in[0];  // [4,2048,1024]
    const float* w1 = (const float*)d_in[1];  // [4096,1024]
    const float* cw = (const float*)d_in[2];  // [4096,1,3]
    const float* cb = (const float*)d_in[3];  // [4096]
    const float* w2 = (const float*)d_in[4];  // [1024,4096]
    float* out = (float*)d_out;               // [4,2048,1024]
    char* ws = (char*)d_ws;

    // Workspace layout (16B-aligned)
    double* part  = (double*)(ws + 0);          // 2048 doubles
    float*  sc    = (float*)(ws + 16384);       // {scale_w1, dq_w1, scale_w2, dq_w2}
    float*  dqx   = (float*)(ws + 16640);       // 8192 floats
    float*  dqh   = (float*)(ws + 49408);       // 8192 floats
    int8_t* qw1   = (int8_t*)(ws + 82176);      // 4 MB
    int8_t* qw2   = (int8_t*)(ws + 4276480);    // 4 MB
    int8_t* qx    = (int8_t*)(ws + 8470784);    // 8 MB
    int8_t* qh    = (int8_t*)(ws + 16859392);   // 32 MB
    _Float16* h   = (_Float16*)(ws + 50413824); // 64 MB (fp16)

    absmean_partial<<<2048, 256, 0, stream>>>((const float4*)w1, (const float4*)w2, part);
    finalize_scales<<<1, 256, 0, stream>>>(part, sc);
    quant_all<<<16384, 256, 0, stream>>>((const float4*)w1, (const float4*)w2,
                                         (const float4*)x, (char4*)qw1, (char4*)qw2,
                                         (char4*)qx, dqx, sc);

    // GEMM1: M=8192, N=4096, K=1024 -> h (fp16); 1024 blocks, 2 blocks/CU
    dim3 g1(DH / 128, NTOK / 256);
    gemm_i8_bk64<256, 8, _Float16><<<g1, 512, 0, stream>>>(qx, qw1, h, dqx, sc, 1, DH, DM);

    conv_silu_quant<<<NTOK / CT, 512, 0, stream>>>((const half8*)h, (const float4*)cw,
                                                   (const float4*)cb, (char8v*)qh, dqh);

    // GEMM2: M=8192, N=1024, K=4096 -> out (fp32); 512 blocks, 3 blocks/CU
    dim3 g2(DM / 128, NTOK / 128);
    gemm_i8_bk64<128, 4, float><<<g2, 256, 0, stream>>>(qh, qw2, out, dqh, sc, 3, DM, DH);
}

// Round 3
// 232.426 us; speedup vs baseline: 1.1812x; 1.0632x over previous
//
#include <hip/hip_runtime.h>
#include <cstdint>

// Problem sizes (fixed by reference)
#define S_    2048
#define DM    1024
#define DH    4096
#define NTOK  8192     // B*S = 4*2048
#define WELEM 4194304  // 4096*1024 elements in each weight matrix
#define CT    8        // tokens per conv block

typedef int v4i __attribute__((ext_vector_type(4)));
typedef _Float16 half8 __attribute__((ext_vector_type(8)));
typedef char char8v __attribute__((ext_vector_type(8)));

// async global->LDS, 16B per lane, dest = wave-uniform base (+ lane*16 by HW)
#define GLOAD_LDS16(g, l)                                                   \
    __builtin_amdgcn_global_load_lds(                                       \
        (const __attribute__((address_space(1))) void*)(g),                 \
        (__attribute__((address_space(3))) void*)(l), 16, 0, 0)

// raw barrier (no implicit vmcnt(0) drain) + compiler memory fence
static __device__ __forceinline__ void sbar() {
    asm volatile("" ::: "memory");
    __builtin_amdgcn_s_barrier();
    asm volatile("" ::: "memory");
}
#define VMC0() asm volatile("s_waitcnt vmcnt(0)" ::: "memory")
#define VMC3() asm volatile("s_waitcnt vmcnt(3)" ::: "memory")
#define VMC4() asm volatile("s_waitcnt vmcnt(4)" ::: "memory")

// ---------------------------------------------------------------------------
// Per-block partial sums of |w| in fp64, both matrices in one launch.
__global__ __launch_bounds__(256) void absmean_partial(const float4* __restrict__ wa,
                                                       const float4* __restrict__ wb,
                                                       double* __restrict__ partial) {
    __shared__ double red[256];
    const float4* w = (blockIdx.x < 1024) ? wa : wb;
    int base = (blockIdx.x & 1023) * 1024;  // in float4 units
    double s = 0.0;
#pragma unroll
    for (int k = 0; k < 4; ++k) {
        float4 v = w[base + (k << 8) + threadIdx.x];
        s += (double)fabsf(v.x) + (double)fabsf(v.y) +
             (double)fabsf(v.z) + (double)fabsf(v.w);
    }
    red[threadIdx.x] = s;
    __syncthreads();
    for (int off = 128; off > 0; off >>= 1) {
        if (threadIdx.x < off) red[threadIdx.x] += red[threadIdx.x + off];
        __syncthreads();
    }
    if (threadIdx.x == 0) partial[blockIdx.x] = red[0];
}

// Deterministic tree-sum of partials; scale = 1/clip(mean,1e-5) fp32.
__global__ __launch_bounds__(256) void finalize_scales(const double* __restrict__ part,
                                                       float* __restrict__ sc) {
    __shared__ double red[1024];
#pragma unroll 1
    for (int m = 0; m < 2; ++m) {
        const double* p = part + m * 1024;
        __syncthreads();
#pragma unroll
        for (int k = 0; k < 4; ++k) red[(k << 8) + threadIdx.x] = p[(k << 8) + threadIdx.x];
        __syncthreads();
        double s = red[threadIdx.x] + red[threadIdx.x + 256] +
                   red[threadIdx.x + 512] + red[threadIdx.x + 768];
        __syncthreads();
        red[threadIdx.x] = s;
        __syncthreads();
        for (int off = 128; off > 0; off >>= 1) {
            if (threadIdx.x < off) red[threadIdx.x] += red[threadIdx.x + off];
            __syncthreads();
        }
        if (threadIdx.x == 0) {
            double mean = red[0] / (double)WELEM;
            float mf = fmaxf((float)mean, 1e-5f);
            float scale = 1.0f / mf;
            sc[2 * m]     = scale;
            sc[2 * m + 1] = 1.0f / scale;
        }
    }
}

// One launch: blocks [0,8192) ternary-quantize w1/w2; [8192,16384) int8-quantize x.
__global__ __launch_bounds__(256) void quant_all(const float4* __restrict__ w1,
                                                 const float4* __restrict__ w2,
                                                 const float4* __restrict__ x,
                                                 char4* __restrict__ qw1,
                                                 char4* __restrict__ qw2,
                                                 char4* __restrict__ qx,
                                                 float* __restrict__ dqx,
                                                 const float* __restrict__ sc) {
    __shared__ float red[256];
    if (blockIdx.x < 8192) {
        bool second = blockIdx.x >= 4096;
        const float4* w = second ? w2 : w1;
        char4* q = second ? qw2 : qw1;
        float scale = sc[second ? 2 : 0];
        int i = (blockIdx.x & 4095) * 256 + threadIdx.x;
        float4 v = w[i];
        char4 o;
        o.x = (signed char)(int)fminf(fmaxf(rintf(v.x * scale), -1.f), 1.f);
        o.y = (signed char)(int)fminf(fmaxf(rintf(v.y * scale), -1.f), 1.f);
        o.z = (signed char)(int)fminf(fmaxf(rintf(v.z * scale), -1.f), 1.f);
        o.w = (signed char)(int)fminf(fmaxf(rintf(v.w * scale), -1.f), 1.f);
        q[i] = o;
    } else {
        int t = blockIdx.x - 8192;
        float4 v = x[(size_t)t * 256 + threadIdx.x];
        float mx = fmaxf(fmaxf(fabsf(v.x), fabsf(v.y)), fmaxf(fabsf(v.z), fabsf(v.w)));
        red[threadIdx.x] = mx;
        __syncthreads();
        for (int off = 128; off > 0; off >>= 1) {
            if (threadIdx.x < off) red[threadIdx.x] = fmaxf(red[threadIdx.x], red[threadIdx.x + off]);
            __syncthreads();
        }
        float scale = 127.0f / fmaxf(red[0], 1e-5f);
        // |v|*scale <= 127 by construction -> clamps redundant
        char4 o;
        o.x = (signed char)(int)rintf(v.x * scale);
        o.y = (signed char)(int)rintf(v.y * scale);
        o.z = (signed char)(int)rintf(v.z * scale);
        o.w = (signed char)(int)rintf(v.w * scale);
        qx[(size_t)t * 256 + threadIdx.x] = o;
        if (threadIdx.x == 0) dqx[t] = 1.0f / scale;
    }
}

// Fused depthwise conv3 (+bias) + SiLU + per-token int8 quant over DH=4096.
// Round-3: VALU diet. SiLU via v_exp_f32/v_rcp_f32 (5 instr vs ~23 for
// ocml expf + exact div); quant clamps dropped (|v*scale| <= 127 by
// construction of scale). Structure unchanged (r2 profile: VALUBusy 70%,
// MfmaUtil 0, HBM 19% -> VALU-bound; SiLU was ~60% of the instr budget).
__global__ __launch_bounds__(512) void conv_silu_quant(const half8* __restrict__ h,
                                                       const float4* __restrict__ cwv,
                                                       const float4* __restrict__ cbv,
                                                       char8v* __restrict__ q,
                                                       float* __restrict__ dq) {
    __shared__ float red[2][8];
    const int tid = threadIdx.x;
    const int t0 = blockIdx.x * CT;
    const int s0 = t0 & (S_ - 1);      // CT | S_, block never straddles batches

    float wc[24], bs[8];
    {
        float4 tmp;
#pragma unroll
        for (int i = 0; i < 6; ++i) {
            tmp = cwv[tid * 6 + i];
            wc[4 * i] = tmp.x; wc[4 * i + 1] = tmp.y; wc[4 * i + 2] = tmp.z; wc[4 * i + 3] = tmp.w;
        }
        tmp = cbv[tid * 2];     bs[0] = tmp.x; bs[1] = tmp.y; bs[2] = tmp.z; bs[3] = tmp.w;
        tmp = cbv[tid * 2 + 1]; bs[4] = tmp.x; bs[5] = tmp.y; bs[6] = tmp.z; bs[7] = tmp.w;
    }

    auto ldrow = [&](int t, bool valid, float* dst) {
        if (valid) {
            half8 raw = h[(size_t)t * 512 + tid];
#pragma unroll
            for (int e = 0; e < 8; ++e) dst[e] = (float)raw[e];
        } else {
#pragma unroll
            for (int e = 0; e < 8; ++e) dst[e] = 0.f;
        }
    };

    float pv[8], cu[8], nx[8], pf[8];
    ldrow(t0 - 1, s0 > 0, pv);
    ldrow(t0, true, cu);
    ldrow(t0 + 1, true, nx);

#pragma unroll
    for (int i = 0; i < CT; ++i) {
        const int t = t0 + i;
        ldrow(t + 2, (s0 + i + 2) < S_, pf);

        float v[8];
        float mx = 0.f;
#pragma unroll
        for (int e = 0; e < 8; ++e) {
            float y = wc[3 * e] * pv[e] + wc[3 * e + 1] * cu[e] + wc[3 * e + 2] * nx[e] + bs[e];
            // silu(y) = y * sigmoid(y) = y * rcp(1 + 2^(-y*log2e))
            float ex = __builtin_amdgcn_exp2f(-1.44269504088896f * y);
            float r  = y * __builtin_amdgcn_rcpf(1.0f + ex);
            v[e] = r;
            mx = fmaxf(mx, fabsf(r));
        }
#pragma unroll
        for (int off = 32; off > 0; off >>= 1)
            mx = fmaxf(mx, __shfl_down(mx, off, 64));
        if ((tid & 63) == 0) red[i & 1][tid >> 6] = mx;
        __syncthreads();
        float rmax = red[i & 1][0];
#pragma unroll
        for (int w = 1; w < 8; ++w) rmax = fmaxf(rmax, red[i & 1][w]);
        float scale = 127.0f / fmaxf(rmax, 1e-5f);
        // |v|*scale <= 127 by construction -> clamps redundant
        char8v o;
#pragma unroll
        for (int e = 0; e < 8; ++e)
            o[e] = (signed char)(int)rintf(v[e] * scale);
        q[(size_t)t * 512 + tid] = o;
        if (tid == 0) dq[t] = 1.0f / scale;
#pragma unroll
        for (int e = 0; e < 8; ++e) { pv[e] = cu[e]; cu[e] = nx[e]; nx[e] = pf[e]; }
    }
}

// ---------------------------------------------------------------------------
// int8 x ternary GEMM, BK=64, one barrier per K-tile, 3-deep ring, occupancy-
// first:  C[m,n] = (sum_k A[m,k]*B[n,k]) * rowdq[m] * sc[slot]
//
// BM=256/W=8 (GEMM1): ring 3 x 24KB = 72KB -> 2 blocks/CU (4 waves/SIMD).
// BM=128/W=4 (GEMM2): ring 3 x 16KB = 48KB -> 3 blocks/CU; grid 512 (full CU
// coverage at N=1024, which BN-only tiling couldn't give).
//
// Protocol (single barrier per tile, counted vmcnt never 0 mid-loop):
//   tile t: ds_read frags(buf t%3) | stage(t+2 -> buf (t+2)%3) |
//           16 x mfma (compiler-inserted fine lgkmcnt) | vmcnt(L) | s_barrier
// Recycle safety: any wave past barrier(t) finished its MFMAs(t), hence its
// ds_reads(t) completed; stage(t+3) into buf t%3 is issued only after
// barrier(t). vmcnt(L) at barrier(t) retires tile t+1's loads (its own L
// newest, tile t+2's, remain in flight); barrier makes that cross-wave safe.
//
// Swizzle (64B LDS rows): phys_chunk = chunk ^ ((row>>1)&3). Involution,
// applied on the global staging source (linear DMA dest) and on ds_read.
// 16-lane frag groups spread over all 8 bank-slot classes exactly 2x
// (2-way aliasing is free, m136).
template <int BM, int WAVES, typename OutT>
__global__ __launch_bounds__(WAVES * 64, (BM == 256) ? 4 : 3)
void gemm_i8_bk64(const int8_t* __restrict__ A, const int8_t* __restrict__ Bm,
                  OutT* __restrict__ C, const float* __restrict__ rowdq,
                  const float* __restrict__ sc, int slot, int N, int K) {
    constexpr int BN = 128;
    constexpr int ABYTES = BM * 64;           // A bytes per ring buffer
    constexpr int BUF = (BM + BN) * 64;       // bytes per ring buffer
    constexpr int ALOADS = BM / 16 / WAVES;   // per-wave 1KB A loads per tile
    constexpr int BLOADS = BN / 16 / WAVES;   // per-wave 1KB B loads per tile
    constexpr int L = ALOADS + BLOADS;        // per-wave loads per tile

    __shared__ __align__(16) int8_t lds[3][BUF];
    const int tid  = threadIdx.x;
    const int lane = tid & 63;
    const int wave = tid >> 6;

    // XCD-chunked bijective swizzle (both grids are multiples of 8)
    const int nwg = gridDim.x * gridDim.y;
    int flat = blockIdx.y * gridDim.x + blockIdx.x;
    flat = (flat & 7) * (nwg >> 3) + (flat >> 3);
    const int bx = flat % gridDim.x;
    const int by = flat / gridDim.x;
    const int mbase = by * BM;
    const int nbase = bx << 7;
    const int NT = K >> 6;

    const int wm = wave >> 1;                 // m 64-row slab
    const int wn = wave & 1;                  // n 64-col half

    // ---- staging source addressing (inverse swizzle on global side)
    const int srow = lane >> 2;                               // row within 1KB load
    const int csrc = (((lane & 3) ^ ((lane >> 3) & 3)) << 4); // logical 16B chunk
    const int8_t* Ag = A  + (size_t)(mbase + wave * (ALOADS * 16) + srow) * K + csrc;
    const int8_t* Bg = Bm + (size_t)(nbase + wave * (BLOADS * 16) + srow) * K + csrc;

    auto stage = [&](int s, int tt) {
        const size_t ko = (size_t)tt << 6;
        int8_t* dA = &lds[s][(wave * ALOADS) << 10];
        int8_t* dB = &lds[s][ABYTES + ((wave * BLOADS) << 10)];
#pragma unroll
        for (int l = 0; l < ALOADS; ++l)
            GLOAD_LDS16(Ag + ko + (size_t)(l * 16) * K, dA + (l << 10));
#pragma unroll
        for (int l = 0; l < BLOADS; ++l)
            GLOAD_LDS16(Bg + ko + (size_t)(l * 16) * K, dB + (l << 10));
    };

    // ---- frag read offsets (i8 16x16x64: row = lane&15, chunk = lane>>4)
    const int fc   = (((lane >> 4) ^ ((lane >> 1) & 3)) << 4);  // swizzled chunk
    const int aoff = ((wm * 64 + (lane & 15)) << 6) + fc;       // + i*1024
    const int boff = ABYTES + ((wn * 64 + (lane & 15)) << 6) + fc;

    v4i acc[4][4] = {};

    // prologue: 2 tiles in flight; wait tile 0 (counted), cross-wave via barrier
    stage(0, 0);
    stage(1, 1);
    if constexpr (L == 3) VMC3(); else VMC4();
    sbar();

    int sb = 0;
    for (int t = 0; t < NT; ++t) {
        const int8_t* base = &lds[sb][0];
        v4i af[4], bf[4];
#pragma unroll
        for (int i = 0; i < 4; ++i)
            af[i] = *reinterpret_cast<const v4i*>(base + aoff + (i << 10));
#pragma unroll
        for (int j = 0; j < 4; ++j)
            bf[j] = *reinterpret_cast<const v4i*>(base + boff + (j << 10));
        int s2 = sb + 2; if (s2 >= 3) s2 -= 3;
        if (t + 2 < NT) stage(s2, t + 2);

        __builtin_amdgcn_s_setprio(1);
#pragma unroll
        for (int i = 0; i < 4; ++i)
#pragma unroll
            for (int j = 0; j < 4; ++j)
                acc[i][j] = __builtin_amdgcn_mfma_i32_16x16x64_i8(af[i], bf[j], acc[i][j], 0, 0, 0);
        __builtin_amdgcn_s_setprio(0);

        if (t + 2 < NT)      { if constexpr (L == 3) VMC3(); else VMC4(); }
        else if (t + 1 < NT) VMC0();
        sbar();
        if (++sb == 3) sb = 0;
    }

    // ---------------- epilogue ----------------
    const float wdq = sc[slot];
    const int quad = lane >> 4;
    const int col  = lane & 15;
#pragma unroll
    for (int i = 0; i < 4; ++i) {
#pragma unroll
        for (int r = 0; r < 4; ++r) {
            int m = mbase + (wm << 6) + (i << 4) + (quad << 2) + r;  // row=(lane>>4)*4+reg
            float rs = rowdq[m] * wdq;
#pragma unroll
            for (int j = 0; j < 4; ++j) {
                int n = nbase + (wn << 6) + (j << 4) + col;          // col=lane&15
                C[(size_t)m * N + n] = (OutT)((float)acc[i][j][r] * rs);
            }
        }
    }
}

// ---------------------------------------------------------------------------
extern "C" void kernel_launch(void* const* d_in, const int* in_sizes, int n_in,
                              void* d_out, int out_size, void* d_ws, size_t ws_size,
                              hipStream_t stream) {
    const float* x  = (const float*)d_in[0];  // [4,2048,1024]
    const float* w1 = (const float*)d_in[1];  // [4096,1024]
    const float* cw = (const float*)d_in[2];  // [4096,1,3]
    const float* cb = (const float*)d_in[3];  // [4096]
    const float* w2 = (const float*)d_in[4];  // [1024,4096]
    float* out = (float*)d_out;               // [4,2048,1024]
    char* ws = (char*)d_ws;

    // Workspace layout (16B-aligned)
    double* part  = (double*)(ws + 0);          // 2048 doubles
    float*  sc    = (float*)(ws + 16384);       // {scale_w1, dq_w1, scale_w2, dq_w2}
    float*  dqx   = (float*)(ws + 16640);       // 8192 floats
    float*  dqh   = (float*)(ws + 49408);       // 8192 floats
    int8_t* qw1   = (int8_t*)(ws + 82176);      // 4 MB
    int8_t* qw2   = (int8_t*)(ws + 4276480);    // 4 MB
    int8_t* qx    = (int8_t*)(ws + 8470784);    // 8 MB
    int8_t* qh    = (int8_t*)(ws + 16859392);   // 32 MB
    _Float16* h   = (_Float16*)(ws + 50413824); // 64 MB (fp16)

    absmean_partial<<<2048, 256, 0, stream>>>((const float4*)w1, (const float4*)w2, part);
    finalize_scales<<<1, 256, 0, stream>>>(part, sc);
    quant_all<<<16384, 256, 0, stream>>>((const float4*)w1, (const float4*)w2,
                                         (const float4*)x, (char4*)qw1, (char4*)qw2,
                                         (char4*)qx, dqx, sc);

    // GEMM1: M=8192, N=4096, K=1024 -> h (fp16); 1024 blocks, 2 blocks/CU
    dim3 g1(DH / 128, NTOK / 256);
    gemm_i8_bk64<256, 8, _Float16><<<g1, 512, 0, stream>>>(qx, qw1, h, dqx, sc, 1, DH, DM);

    conv_silu_quant<<<NTOK / CT, 512, 0, stream>>>((const half8*)h, (const float4*)cw,
                                                   (const float4*)cb, (char8v*)qh, dqh);

    // GEMM2: M=8192, N=1024, K=4096 -> out (fp32); 512 blocks, 3 blocks/CU
    dim3 g2(DM / 128, NTOK / 128);
    gemm_i8_bk64<128, 4, float><<<g2, 256, 0, stream>>>(qh, qw2, out, dqh, sc, 3, DM, DH);
}